// Round 9
// baseline (592.772 us; speedup 1.0000x reference)
//
#include <hip/hip_runtime.h>

#define D_IN 50
#define LN_EPS 1e-5f
#define BSH 8           // 256 nodes per bucket
#define MAXB 512        // max buckets (N <= 131072)
#define NSLOT 64        // scattered LN-stat atomic slots (64B apart)

typedef __bf16 bf16_t;
typedef bf16_t bf16x8 __attribute__((ext_vector_type(8)));
typedef float f32x4_t __attribute__((ext_vector_type(4)));
typedef float f32x2_t __attribute__((ext_vector_type(2)));

// accumulate 4 u32 (8 bf16) into 4 packed float2 accumulators (v_pk_add_f32)
#define ACCP(r, A)                                                            \
    {                                                                         \
        A[0] += (f32x2_t){__uint_as_float((r).x << 16),                       \
                          __uint_as_float((r).x & 0xffff0000u)};              \
        A[1] += (f32x2_t){__uint_as_float((r).y << 16),                       \
                          __uint_as_float((r).y & 0xffff0000u)};              \
        A[2] += (f32x2_t){__uint_as_float((r).z << 16),                       \
                          __uint_as_float((r).z & 0xffff0000u)};              \
        A[3] += (f32x2_t){__uint_as_float((r).w << 16),                       \
                          __uint_as_float((r).w & 0xffff0000u)};              \
    }

// ---------------------------------------------------------------- CSR build
__global__ void bucket_hist_k(const int* __restrict__ dst, int* __restrict__ bcnt,
                              double* __restrict__ lnacc, int e, int nb) {
    __shared__ int lh[MAXB];
    int t = threadIdx.x;
    if (blockIdx.x == 0 && t < 3 * NSLOT) {     // re-zero 3 layers x 64 slots
        lnacc[t * 8] = 0.0;
        lnacc[t * 8 + 1] = 0.0;
    }
    for (int i = t; i < nb; i += 256) lh[i] = 0;
    __syncthreads();
    for (int i = blockIdx.x * 256 + t; i < e; i += gridDim.x * 256)
        atomicAdd(&lh[dst[i] >> BSH], 1);
    __syncthreads();
    for (int i = t; i < nb; i += 256) {
        int c = lh[i];
        if (c) atomicAdd(&bcnt[i * 16], c);
    }
}

__global__ void bscan_k(const int* __restrict__ bcnt, int* __restrict__ boff,
                        int* __restrict__ bpos, int nb, int e) {
    __shared__ int l[MAXB];
    int t = threadIdx.x;
    l[t] = (t < nb) ? bcnt[t * 16] : 0;
    __syncthreads();
    for (int off = 1; off < MAXB; off <<= 1) {
        int v = (t >= off) ? l[t - off] : 0;
        __syncthreads();
        l[t] += v;
        __syncthreads();
    }
    int excl = (t > 0) ? l[t - 1] : 0;
    if (t < nb) { boff[t] = excl; bpos[t * 16] = excl; }
    if (t == 0) boff[nb] = e;
}

__global__ void scatter_k(const int* __restrict__ src, const int* __restrict__ dst,
                          int* __restrict__ bpos, unsigned* __restrict__ pool,
                          int e, int nb) {
    __shared__ int lh[MAXB];
    __shared__ int lcur[MAXB];
    int t = threadIdx.x;
    for (int i = t; i < nb; i += 256) lh[i] = 0;
    __syncthreads();
    int chunk = (e + gridDim.x - 1) / gridDim.x;
    int s = blockIdx.x * chunk;
    int en = min(e, s + chunk);
    for (int i = s + t; i < en; i += 256)
        atomicAdd(&lh[dst[i] >> BSH], 1);
    __syncthreads();
    for (int i = t; i < nb; i += 256) {
        int c = lh[i];
        lcur[i] = c ? atomicAdd(&bpos[i * 16], c) : 0;
    }
    __syncthreads();
    for (int i = s + t; i < en; i += 256) {
        int d = dst[i];
        int p = atomicAdd(&lcur[d >> BSH], 1);
        pool[p] = (unsigned)src[i] | ((unsigned)(d & 255) << 17);
    }
}

__global__ void nhist_cfill_k(const unsigned* __restrict__ pool, const int* __restrict__ boff,
                              int* __restrict__ rp, int* __restrict__ col, int n) {
    __shared__ int lc[256];
    __shared__ int ls[256];
    __shared__ int lpos[256];
    int b = blockIdx.x, t = threadIdx.x;
    lc[t] = 0;
    __syncthreads();
    int s = boff[b], e = boff[b + 1];
    for (int i = s + t; i < e; i += 256) atomicAdd(&lc[pool[i] >> 17], 1);
    __syncthreads();
    int v = lc[t];
    ls[t] = v;
    __syncthreads();
    for (int off = 1; off < 256; off <<= 1) {
        int x = (t >= off) ? ls[t - off] : 0;
        __syncthreads();
        ls[t] += x;
        __syncthreads();
    }
    int excl = ls[t] - v;
    int nd = (b << BSH) + t;
    if (nd < n) rp[nd] = s + excl;
    if (nd == n - 1) rp[n] = e;
    lpos[t] = s + excl;
    __syncthreads();
    for (int i = s + t; i < e; i += 256) {
        unsigned pk = pool[i];
        int slot = atomicAdd(&lpos[pk >> 17], 1);
        col[slot] = (int)(pk & 0x1FFFFu);
    }
}

// -------------------------------------------------------------- converters
struct ConvDesc { const float* w; bf16_t* o; int kin; int kpad; };
struct ConvArgs { ConvDesc d[8]; };

__global__ void conv_w_k(ConvArgs args) {
    ConvDesc d = args.d[blockIdx.y];
    int i = blockIdx.x * 256 + threadIdx.x;
    int tot = 128 * d.kpad;
    if (i >= tot) return;
    int n = i / d.kpad, k = i - n * d.kpad;
    float v = (k < d.kin) ? d.w[(size_t)k * 128 + n] : 0.f;
    d.o[i] = (bf16_t)v;
}

__global__ void conv_x_k(const float* __restrict__ x, bf16_t* __restrict__ xb, int n) {
    int i = blockIdx.x * 256 + threadIdx.x;
    if (i >= n * 64) return;
    int node = i >> 6, k = i & 63;
    xb[i] = (k < D_IN) ? (bf16_t)x[node * D_IN + k] : (bf16_t)0.f;
}

// ------------------------------------------------------------- aggregation
// At the structural service-rate ceiling (~7.2 TB/s delivered) — do not
// restructure (rounds 3/4 both regressed trading parallelism for locality).
__global__ void agg_bf64_k(const bf16_t* __restrict__ feat, const int* __restrict__ rp,
                           const int* __restrict__ col, bf16_t* __restrict__ mean, int n) {
    int wid = (blockIdx.x * blockDim.x + threadIdx.x) >> 6;
    int lane = threadIdx.x & 63;
    if (wid >= n) return;
    int start = rp[wid], end = rp[wid + 1];
    int lc = lane & 7;
    int g = lane >> 3;
    f32x2_t accA[4], accB[4];
#pragma unroll
    for (int k = 0; k < 4; k++) { accA[k] = (f32x2_t){0.f, 0.f}; accB[k] = (f32x2_t){0.f, 0.f}; }
    int e = start + g;
    if (e + 8 < end) {
        int i0 = col[e], i1 = col[e + 8];
        for (; e + 24 < end; e += 16) {
            uint4 r0 = *(const uint4*)(feat + (size_t)i0 * 64 + lc * 8);
            uint4 r1 = *(const uint4*)(feat + (size_t)i1 * 64 + lc * 8);
            i0 = col[e + 16];
            i1 = col[e + 24];
            ACCP(r0, accA);
            ACCP(r1, accB);
        }
        uint4 r0 = *(const uint4*)(feat + (size_t)i0 * 64 + lc * 8);
        uint4 r1 = *(const uint4*)(feat + (size_t)i1 * 64 + lc * 8);
        ACCP(r0, accA);
        ACCP(r1, accB);
        e += 16;
    }
    for (; e < end; e += 8) {
        uint4 r0 = *(const uint4*)(feat + (size_t)col[e] * 64 + lc * 8);
        ACCP(r0, accA);
    }
#pragma unroll
    for (int k = 0; k < 4; k++) accA[k] += accB[k];
    float aL[4], aH[4];
#pragma unroll
    for (int k = 0; k < 4; k++) { aL[k] = accA[k].x; aH[k] = accA[k].y; }
#pragma unroll
    for (int off = 8; off < 64; off <<= 1) {
#pragma unroll
        for (int k = 0; k < 4; k++) {
            aL[k] += __shfl_xor(aL[k], off);
            aH[k] += __shfl_xor(aH[k], off);
        }
    }
    int c = end - start;
    float invc = 1.f / (float)(c > 0 ? c : 1);
    if (lane < 8) {
        bf16x8 o;
#pragma unroll
        for (int k = 0; k < 4; k++) {
            o[2 * k] = (bf16_t)(aL[k] * invc);
            o[2 * k + 1] = (bf16_t)(aH[k] * invc);
        }
        *(bf16x8*)(mean + (size_t)wid * 64 + lc * 8) = o;
    }
}

// 4-deep pipelined gather (round-2 best: 56.6 us).
__global__ void agg_bf128_k(const bf16_t* __restrict__ feat, const int* __restrict__ rp,
                            const int* __restrict__ col, bf16_t* __restrict__ mean, int n) {
    int wid = (blockIdx.x * blockDim.x + threadIdx.x) >> 6;
    int lane = threadIdx.x & 63;
    if (wid >= n) return;
    int start = rp[wid], end = rp[wid + 1];
    int lc = lane & 15;
    int g = lane >> 4;
    const uint* fp = (const uint*)feat + lc * 4;   // row stride = 64 uints
    f32x2_t accA[4], accB[4];
#pragma unroll
    for (int k = 0; k < 4; k++) { accA[k] = (f32x2_t){0.f, 0.f}; accB[k] = (f32x2_t){0.f, 0.f}; }
    int e = start + g;
    int ng = (e < end) ? (((end - 1 - e) >> 2) + 1) : 0;
    int it = 0;
    for (; it + 4 <= ng; it += 4, e += 16) {
        int a = col[e], b = col[e + 4], c = col[e + 8], d = col[e + 12];
        uint4 r0 = *(const uint4*)(fp + (size_t)a * 64);
        uint4 r1 = *(const uint4*)(fp + (size_t)b * 64);
        uint4 r2 = *(const uint4*)(fp + (size_t)c * 64);
        uint4 r3 = *(const uint4*)(fp + (size_t)d * 64);
        ACCP(r0, accA);
        ACCP(r1, accB);
        ACCP(r2, accA);
        ACCP(r3, accB);
    }
    int rem = ng - it;
    if (rem > 0) {
        int a = col[e];
        int b = (rem > 1) ? col[e + 4] : a;
        int c = (rem > 2) ? col[e + 8] : b;
        uint4 r0 = *(const uint4*)(fp + (size_t)a * 64);
        uint4 r1 = *(const uint4*)(fp + (size_t)b * 64);
        uint4 r2 = *(const uint4*)(fp + (size_t)c * 64);
        ACCP(r0, accA);
        if (rem > 1) ACCP(r1, accB);
        if (rem > 2) ACCP(r2, accA);
    }
#pragma unroll
    for (int k = 0; k < 4; k++) accA[k] += accB[k];
    float aL[4], aH[4];
#pragma unroll
    for (int k = 0; k < 4; k++) { aL[k] = accA[k].x; aH[k] = accA[k].y; }
#pragma unroll
    for (int off = 16; off < 64; off <<= 1) {
#pragma unroll
        for (int k = 0; k < 4; k++) {
            aL[k] += __shfl_xor(aL[k], off);
            aH[k] += __shfl_xor(aH[k], off);
        }
    }
    int c = end - start;
    float invc = 1.f / (float)(c > 0 ? c : 1);
    if (lane < 16) {
        bf16x8 o;
#pragma unroll
        for (int k = 0; k < 4; k++) {
            o[2 * k] = (bf16_t)(aL[k] * invc);
            o[2 * k + 1] = (bf16_t)(aH[k] * invc);
        }
        *(bf16x8*)(mean + (size_t)wid * 128 + lc * 8) = o;
    }
}

// ------------------------------------------------- fused SAGE linear (MFMA)
// 16 rows/wave (64 rows/block): grid 782->1563 blocks, ~6 blocks/CU ->
// occupancy ceiling 37%->75% (GEMMs were grid-limited latency-bound at
// 14-22% occ). Weights L2-direct (zero LDS; round 7 proved time-neutral vs
// LDS, and LDS weights would re-cap blocks/CU at 2). Scattered-slot atomics.
template <int KPAD, bool DUAL>
__global__ __launch_bounds__(256) void mfma_gemm_k(
    const bf16_t* __restrict__ A, const bf16_t* __restrict__ B,
    const bf16_t* __restrict__ WlT, const bf16_t* __restrict__ WrT,
    const float* __restrict__ bias,
    bf16_t* __restrict__ out, double* __restrict__ lnacc, int M) {
    constexpr int KC = KPAD / 32;
    __shared__ float rsum[4], rsum2[4];

    const int tid = threadIdx.x;
    const int w = tid >> 6;
    const int wid = blockIdx.x * 4 + w;
    const int lane = tid & 63;
    const int row0 = wid * 16;
    const int m = lane & 15;
    const int q = lane >> 4;
    const bool act = row0 < M;

    float lsum = 0.f, lsum2 = 0.f;
    if (act) {
        bf16x8 af[KC], bfr[DUAL ? KC : 1];
        {
            const bf16_t* ar = A + (size_t)(row0 + m) * KPAD + q * 8;
#pragma unroll
            for (int c = 0; c < KC; c++) af[c] = *(const bf16x8*)(ar + c * 32);
            if (DUAL) {
                const bf16_t* br = B + (size_t)(row0 + m) * KPAD + q * 8;
#pragma unroll
                for (int c = 0; c < KC; c++) bfr[c] = *(const bf16x8*)(br + c * 32);
            }
        }
#pragma unroll
        for (int nt = 0; nt < 8; nt++) {
            f32x4_t acc = {0.f, 0.f, 0.f, 0.f};
            const bf16_t* wb1 = WlT + (size_t)(nt * 16 + m) * KPAD + q * 8;
            const bf16_t* wb2 = WrT + (size_t)(nt * 16 + m) * KPAD + q * 8;
#pragma unroll
            for (int c = 0; c < KC; c++) {
                bf16x8 wl = *(const bf16x8*)(wb1 + c * 32);
                acc = __builtin_amdgcn_mfma_f32_16x16x32_bf16(af[c], wl, acc, 0, 0, 0);
            }
            if (DUAL) {
#pragma unroll
                for (int c = 0; c < KC; c++) {
                    bf16x8 wr = *(const bf16x8*)(wb2 + c * 32);
                    acc = __builtin_amdgcn_mfma_f32_16x16x32_bf16(bfr[c], wr, acc, 0, 0, 0);
                }
            }
            float bv = bias ? bias[nt * 16 + m] : 0.f;
#pragma unroll
            for (int r = 0; r < 4; r++) {
                int row = row0 + q * 4 + r;
                if (row < M) {
                    float o = acc[r] + bv;
                    out[(size_t)row * 128 + nt * 16 + m] = (bf16_t)o;
                    lsum += o; lsum2 += o * o;
                }
            }
        }
    }
    for (int off = 32; off > 0; off >>= 1) {
        lsum += __shfl_down(lsum, off);
        lsum2 += __shfl_down(lsum2, off);
    }
    if (lane == 0) { rsum[w] = lsum; rsum2[w] = lsum2; }
    __syncthreads();
    if (tid == 0) {
        double s = (double)rsum[0] + (double)rsum[1] + (double)rsum[2] + (double)rsum[3];
        double s2 = (double)rsum2[0] + (double)rsum2[1] + (double)rsum2[2] + (double)rsum2[3];
        int slot = (blockIdx.x & (NSLOT - 1)) * 8;
        unsafeAtomicAdd(&lnacc[slot], s);
        unsafeAtomicAdd(&lnacc[slot + 1], s2);
    }
}

// Layer-1 triple, 16 rows/wave, zero-LDS: 3 accumulators per nt-tile
// (P, C1, C2), all 4 weight matrices L2-direct. KPAD=64.
__global__ __launch_bounds__(256) void mfma_gemm3_k(
    const bf16_t* __restrict__ A, const bf16_t* __restrict__ B,
    const bf16_t* __restrict__ WlT, const bf16_t* __restrict__ WrT,
    const bf16_t* __restrict__ Ws1T, const bf16_t* __restrict__ Ws2T,
    const float* __restrict__ bias,
    bf16_t* __restrict__ outP, bf16_t* __restrict__ outC1, bf16_t* __restrict__ outC2,
    double* __restrict__ lnacc, int M) {
    constexpr int KC = 2;
    __shared__ float rsum[4], rsum2[4];

    const int tid = threadIdx.x;
    const int w = tid >> 6;
    const int wid = blockIdx.x * 4 + w;
    const int lane = tid & 63;
    const int row0 = wid * 16;
    const int m = lane & 15;
    const int q = lane >> 4;
    const bool act = row0 < M;

    float lsum = 0.f, lsum2 = 0.f;
    if (act) {
        bf16x8 af[KC], bfr[KC];
        {
            const bf16_t* ar = A + (size_t)(row0 + m) * 64 + q * 8;
            const bf16_t* br = B + (size_t)(row0 + m) * 64 + q * 8;
#pragma unroll
            for (int c = 0; c < KC; c++) {
                af[c] = *(const bf16x8*)(ar + c * 32);
                bfr[c] = *(const bf16x8*)(br + c * 32);
            }
        }
#pragma unroll
        for (int nt = 0; nt < 8; nt++) {
            f32x4_t aP = {0.f, 0.f, 0.f, 0.f};
            f32x4_t a1 = {0.f, 0.f, 0.f, 0.f};
            f32x4_t a2 = {0.f, 0.f, 0.f, 0.f};
            size_t wb = (size_t)(nt * 16 + m) * 64 + q * 8;
#pragma unroll
            for (int c = 0; c < KC; c++) {
                bf16x8 wl = *(const bf16x8*)(WlT + wb + c * 32);
                bf16x8 wr = *(const bf16x8*)(WrT + wb + c * 32);
                bf16x8 w1 = *(const bf16x8*)(Ws1T + wb + c * 32);
                bf16x8 w2 = *(const bf16x8*)(Ws2T + wb + c * 32);
                aP = __builtin_amdgcn_mfma_f32_16x16x32_bf16(af[c], wl, aP, 0, 0, 0);
                aP = __builtin_amdgcn_mfma_f32_16x16x32_bf16(bfr[c], wr, aP, 0, 0, 0);
                a1 = __builtin_amdgcn_mfma_f32_16x16x32_bf16(bfr[c], w1, a1, 0, 0, 0);
                a2 = __builtin_amdgcn_mfma_f32_16x16x32_bf16(bfr[c], w2, a2, 0, 0, 0);
            }
            float bv = bias[nt * 16 + m];
#pragma unroll
            for (int r = 0; r < 4; r++) {
                int row = row0 + q * 4 + r;
                if (row < M) {
                    float o = aP[r] + bv;
                    size_t oi = (size_t)row * 128 + nt * 16 + m;
                    outP[oi] = (bf16_t)o;
                    outC1[oi] = (bf16_t)a1[r];
                    outC2[oi] = (bf16_t)a2[r];
                    lsum += o; lsum2 += o * o;
                }
            }
        }
    }
    for (int off = 32; off > 0; off >>= 1) {
        lsum += __shfl_down(lsum, off);
        lsum2 += __shfl_down(lsum2, off);
    }
    if (lane == 0) { rsum[w] = lsum; rsum2[w] = lsum2; }
    __syncthreads();
    if (tid == 0) {
        double s = (double)rsum[0] + (double)rsum[1] + (double)rsum[2] + (double)rsum[3];
        double s2 = (double)rsum2[0] + (double)rsum2[1] + (double)rsum2[2] + (double)rsum2[3];
        int slot = (blockIdx.x & (NSLOT - 1)) * 8;
        unsafeAtomicAdd(&lnacc[slot], s);
        unsafeAtomicAdd(&lnacc[slot + 1], s2);
    }
}

// --------------------------------------------- LN (graph mode) + PReLU (+skip)
// Slot-reduce preamble (wave 0 folds the 64 scattered stat slots).
template <int MODE>
__global__ void ln_prelu_k(const bf16_t* __restrict__ pre, const bf16_t* __restrict__ h1in,
                           const bf16_t* __restrict__ s,
                           const float* __restrict__ lnw, const float* __restrict__ lnb,
                           const float* __restrict__ a_ptr, const double* __restrict__ acc,
                           void* __restrict__ out0v, void* __restrict__ out1v, int total) {
    __shared__ double ssum, ssum2;
    int t = threadIdx.x;
    if (t < 64) {
        double a = acc[t * 8];
        double b = acc[t * 8 + 1];
        for (int off = 32; off > 0; off >>= 1) {
            a += __shfl_down(a, off);
            b += __shfl_down(b, off);
        }
        if (t == 0) { ssum = a; ssum2 = b; }
    }
    __syncthreads();
    int i = blockIdx.x * blockDim.x + t;
    if (i * 8 >= total) return;
    double cinv = 1.0 / (double)total;
    double mm = ssum * cinv;
    double var = ssum2 * cinv - mm * mm;
    float stdv = (float)sqrt(var > 0.0 ? var : 0.0);
    float scale = 1.0f / (stdv + LN_EPS);
    float mf = (float)mm;
    float a = a_ptr[0];
    int c8 = i & 15;
    float4 w0 = ((const float4*)lnw)[c8 * 2];
    float4 w1 = ((const float4*)lnw)[c8 * 2 + 1];
    float4 b0 = ((const float4*)lnb)[c8 * 2];
    float4 b1 = ((const float4*)lnb)[c8 * 2 + 1];
    float wv[8] = {w0.x, w0.y, w0.z, w0.w, w1.x, w1.y, w1.z, w1.w};
    float bv[8] = {b0.x, b0.y, b0.z, b0.w, b1.x, b1.y, b1.z, b1.w};
    bf16x8 p8 = ((const bf16x8*)pre)[i];
    float h[8];
#pragma unroll
    for (int k = 0; k < 8; k++) {
        float v = ((float)p8[k] - mf) * scale * wv[k] + bv[k];
        h[k] = v >= 0.f ? v : a * v;
    }
    if (MODE == 1) {
        bf16x8 hb, tb;
        bf16x8 sv = ((const bf16x8*)s)[i];
#pragma unroll
        for (int k = 0; k < 8; k++) {
            hb[k] = (bf16_t)h[k];
            tb[k] = (bf16_t)(h[k] + (float)sv[k]);
        }
        ((bf16x8*)out0v)[i] = hb;
        ((bf16x8*)out1v)[i] = tb;
    } else if (MODE == 2) {
        bf16x8 hv = ((const bf16x8*)h1in)[i];
        bf16x8 sv = ((const bf16x8*)s)[i];
        bf16x8 tb;
#pragma unroll
        for (int k = 0; k < 8; k++)
            tb[k] = (bf16_t)((float)hv[k] + h[k] + (float)sv[k]);
        ((bf16x8*)out0v)[i] = tb;
    } else {
        float4 o0 = {h[0], h[1], h[2], h[3]};
        float4 o1 = {h[4], h[5], h[6], h[7]};
        ((float4*)out0v)[i * 2] = o0;
        ((float4*)out0v)[i * 2 + 1] = o1;
    }
}

// ------------------------------------------------------------------ launch
extern "C" void kernel_launch(void* const* d_in, const int* in_sizes, int n_in,
                              void* d_out, int out_size, void* d_ws, size_t ws_size,
                              hipStream_t stream) {
    const float* x    = (const float*)d_in[0];
    const int*   esrc = (const int*)d_in[1];
    const int*   edst = (const int*)d_in[2];
    const float* Wl1  = (const float*)d_in[3];
    const float* Wr1  = (const float*)d_in[4];
    const float* b1   = (const float*)d_in[5];
    const float* Wl2  = (const float*)d_in[6];
    const float* Wr2  = (const float*)d_in[7];
    const float* b2   = (const float*)d_in[8];
    const float* Wl3  = (const float*)d_in[9];
    const float* Wr3  = (const float*)d_in[10];
    const float* b3   = (const float*)d_in[11];
    const float* Ws1  = (const float*)d_in[12];
    const float* Ws2  = (const float*)d_in[13];
    const float* lnw1 = (const float*)d_in[14];
    const float* lnb1 = (const float*)d_in[15];
    const float* lnw2 = (const float*)d_in[16];
    const float* lnb2 = (const float*)d_in[17];
    const float* lnw3 = (const float*)d_in[18];
    const float* lnb3 = (const float*)d_in[19];
    const float* a1   = (const float*)d_in[20];
    const float* a2   = (const float*)d_in[21];
    const float* a3   = (const float*)d_in[22];

    const int N = in_sizes[0] / D_IN;
    const int E = in_sizes[1];
    const int NB = (N + 255) >> BSH;

    char* ws = (char*)d_ws;
    size_t off = 0;
    auto alloc = [&](size_t bytes) -> void* {
        void* p = ws + off;
        off += (bytes + 255) & ~(size_t)255;
        return p;
    };
    bf16_t* xb   = (bf16_t*)alloc((size_t)N * 64 * 2);
    bf16_t* mean = (bf16_t*)alloc((size_t)N * 128 * 2);
    bf16_t* PRE  = (bf16_t*)alloc((size_t)N * 128 * 2);
    bf16_t* C1   = (bf16_t*)alloc((size_t)N * 128 * 2);
    bf16_t* C2   = (bf16_t*)alloc((size_t)N * 128 * 2);
    bf16_t* h1b  = (bf16_t*)alloc((size_t)N * 128 * 2);
    bf16_t* TB   = (bf16_t*)alloc((size_t)N * 128 * 2);
    bf16_t* WT   = (bf16_t*)alloc((size_t)(4 * 128 * 64 + 4 * 128 * 128) * 2);
    int* rp   = (int*)alloc((size_t)(N + 1) * 4);
    int* col  = (int*)alloc((size_t)E * 4);
    int* bcnt = (int*)alloc((size_t)MAXB * 16 * 4);
    int* boff = (int*)alloc((size_t)(MAXB + 1) * 4);
    int* bpos = (int*)alloc((size_t)MAXB * 16 * 4);
    unsigned* pool = (unsigned*)alloc((size_t)E * 4);
    double* lnacc = (double*)alloc((size_t)3 * NSLOT * 8 * 8);   // 3 layers x 64 slots x 64B

    bf16_t* Wl1T = WT;
    bf16_t* Wr1T = Wl1T + 128 * 64;
    bf16_t* Ws1T = Wr1T + 128 * 64;
    bf16_t* Ws2T = Ws1T + 128 * 64;
    bf16_t* Wl2T = Ws2T + 128 * 64;
    bf16_t* Wr2T = Wl2T + 128 * 128;
    bf16_t* Wl3T = Wr2T + 128 * 128;
    bf16_t* Wr3T = Wl3T + 128 * 128;

    hipMemsetAsync(bcnt, 0, (size_t)MAXB * 16 * 4, stream);

    // --- bucketed CSR build (bucket_hist also re-zeros the lnacc slots)
    bucket_hist_k<<<256, 256, 0, stream>>>(edst, bcnt, lnacc, E, NB);
    bscan_k<<<1, MAXB, 0, stream>>>(bcnt, boff, bpos, NB, E);
    scatter_k<<<256, 256, 0, stream>>>(esrc, edst, bpos, pool, E, NB);
    nhist_cfill_k<<<NB, 256, 0, stream>>>(pool, boff, rp, col, N);

    // --- weight/feature conversion
    ConvArgs ca;
    ca.d[0] = {Wl1, Wl1T, 50, 64};
    ca.d[1] = {Wr1, Wr1T, 50, 64};
    ca.d[2] = {Ws1, Ws1T, 50, 64};
    ca.d[3] = {Ws2, Ws2T, 50, 64};
    ca.d[4] = {Wl2, Wl2T, 128, 128};
    ca.d[5] = {Wr2, Wr2T, 128, 128};
    ca.d[6] = {Wl3, Wl3T, 128, 128};
    ca.d[7] = {Wr3, Wr3T, 128, 128};
    conv_w_k<<<dim3(64, 8), 256, 0, stream>>>(ca);
    conv_x_k<<<(N * 64 + 255) / 256, 256, 0, stream>>>(x, xb, N);

    const int aggBlocks = ((N * 64) + 255) / 256;
    const int strips = (N + 15) / 16;
    const int gemmBlocks = (strips + 3) / 4;     // 16 rows/wave, 64 rows/block
    const int lnBlocks = (N * 128 / 8 + 255) / 256;
    const int total = N * 128;
    double* acc1 = lnacc;
    double* acc2 = lnacc + NSLOT * 8;
    double* acc3 = lnacc + 2 * NSLOT * 8;

    // ---- layer 1
    agg_bf64_k<<<aggBlocks, 256, 0, stream>>>(xb, rp, col, mean, N);
    mfma_gemm3_k<<<gemmBlocks, 256, 0, stream>>>(
        mean, xb, Wl1T, Wr1T, Ws1T, Ws2T, b1, PRE, C1, C2, acc1, N);
    ln_prelu_k<1><<<lnBlocks, 256, 0, stream>>>(
        PRE, nullptr, C1, lnw1, lnb1, a1, acc1, h1b, TB, total);

    // ---- layer 2
    agg_bf128_k<<<aggBlocks, 256, 0, stream>>>(TB, rp, col, mean, N);
    mfma_gemm_k<128, true><<<gemmBlocks, 256, 0, stream>>>(
        mean, TB, Wl2T, Wr2T, b2, PRE, acc2, N);
    ln_prelu_k<2><<<lnBlocks, 256, 0, stream>>>(
        PRE, h1b, C2, lnw2, lnb2, a2, acc2, TB, nullptr, total);

    // ---- layer 3
    agg_bf128_k<<<aggBlocks, 256, 0, stream>>>(TB, rp, col, mean, N);
    mfma_gemm_k<128, true><<<gemmBlocks, 256, 0, stream>>>(
        mean, TB, Wl3T, Wr3T, b3, PRE, acc3, N);
    ln_prelu_k<3><<<lnBlocks, 256, 0, stream>>>(
        PRE, nullptr, nullptr, lnw3, lnb3, a3, acc3, d_out, nullptr, total);
}

// Round 10
// 520.633 us; speedup vs baseline: 1.1386x; 1.1386x over previous
//
#include <hip/hip_runtime.h>

#define D_IN 50
#define LN_EPS 1e-5f
#define BSH 8           // 256 nodes per bucket
#define MAXB 512        // max buckets (N <= 131072)
#define NSLOT 64        // scattered LN-stat atomic slots (64B apart)

typedef __bf16 bf16_t;
typedef bf16_t bf16x8 __attribute__((ext_vector_type(8)));
typedef float f32x4_t __attribute__((ext_vector_type(4)));
typedef float f32x2_t __attribute__((ext_vector_type(2)));

#define STRIDE_ST 136   // staging row stride (elems): 272B, 16B-aligned

// accumulate 4 u32 (8 bf16) into 4 packed float2 accumulators (v_pk_add_f32)
#define ACCP(r, A)                                                            \
    {                                                                         \
        A[0] += (f32x2_t){__uint_as_float((r).x << 16),                       \
                          __uint_as_float((r).x & 0xffff0000u)};              \
        A[1] += (f32x2_t){__uint_as_float((r).y << 16),                       \
                          __uint_as_float((r).y & 0xffff0000u)};              \
        A[2] += (f32x2_t){__uint_as_float((r).z << 16),                       \
                          __uint_as_float((r).z & 0xffff0000u)};              \
        A[3] += (f32x2_t){__uint_as_float((r).w << 16),                       \
                          __uint_as_float((r).w & 0xffff0000u)};              \
    }

// ---------------------------------------------------------------- CSR build
__global__ void bucket_hist_k(const int* __restrict__ dst, int* __restrict__ bcnt,
                              double* __restrict__ lnacc, int e, int nb) {
    __shared__ int lh[MAXB];
    int t = threadIdx.x;
    if (blockIdx.x == 0 && t < 3 * NSLOT) {     // re-zero 3 layers x 64 slots
        lnacc[t * 8] = 0.0;
        lnacc[t * 8 + 1] = 0.0;
    }
    for (int i = t; i < nb; i += 256) lh[i] = 0;
    __syncthreads();
    for (int i = blockIdx.x * 256 + t; i < e; i += gridDim.x * 256)
        atomicAdd(&lh[dst[i] >> BSH], 1);
    __syncthreads();
    for (int i = t; i < nb; i += 256) {
        int c = lh[i];
        if (c) atomicAdd(&bcnt[i * 16], c);
    }
}

__global__ void bscan_k(const int* __restrict__ bcnt, int* __restrict__ boff,
                        int* __restrict__ bpos, int nb, int e) {
    __shared__ int l[MAXB];
    int t = threadIdx.x;
    l[t] = (t < nb) ? bcnt[t * 16] : 0;
    __syncthreads();
    for (int off = 1; off < MAXB; off <<= 1) {
        int v = (t >= off) ? l[t - off] : 0;
        __syncthreads();
        l[t] += v;
        __syncthreads();
    }
    int excl = (t > 0) ? l[t - 1] : 0;
    if (t < nb) { boff[t] = excl; bpos[t * 16] = excl; }
    if (t == 0) boff[nb] = e;
}

__global__ void scatter_k(const int* __restrict__ src, const int* __restrict__ dst,
                          int* __restrict__ bpos, unsigned* __restrict__ pool,
                          int e, int nb) {
    __shared__ int lh[MAXB];
    __shared__ int lcur[MAXB];
    int t = threadIdx.x;
    for (int i = t; i < nb; i += 256) lh[i] = 0;
    __syncthreads();
    int chunk = (e + gridDim.x - 1) / gridDim.x;
    int s = blockIdx.x * chunk;
    int en = min(e, s + chunk);
    for (int i = s + t; i < en; i += 256)
        atomicAdd(&lh[dst[i] >> BSH], 1);
    __syncthreads();
    for (int i = t; i < nb; i += 256) {
        int c = lh[i];
        lcur[i] = c ? atomicAdd(&bpos[i * 16], c) : 0;
    }
    __syncthreads();
    for (int i = s + t; i < en; i += 256) {
        int d = dst[i];
        int p = atomicAdd(&lcur[d >> BSH], 1);
        pool[p] = (unsigned)src[i] | ((unsigned)(d & 255) << 17);
    }
}

__global__ void nhist_cfill_k(const unsigned* __restrict__ pool, const int* __restrict__ boff,
                              int* __restrict__ rp, int* __restrict__ col, int n) {
    __shared__ int lc[256];
    __shared__ int ls[256];
    __shared__ int lpos[256];
    int b = blockIdx.x, t = threadIdx.x;
    lc[t] = 0;
    __syncthreads();
    int s = boff[b], e = boff[b + 1];
    for (int i = s + t; i < e; i += 256) atomicAdd(&lc[pool[i] >> 17], 1);
    __syncthreads();
    int v = lc[t];
    ls[t] = v;
    __syncthreads();
    for (int off = 1; off < 256; off <<= 1) {
        int x = (t >= off) ? ls[t - off] : 0;
        __syncthreads();
        ls[t] += x;
        __syncthreads();
    }
    int excl = ls[t] - v;
    int nd = (b << BSH) + t;
    if (nd < n) rp[nd] = s + excl;
    if (nd == n - 1) rp[n] = e;
    lpos[t] = s + excl;
    __syncthreads();
    for (int i = s + t; i < e; i += 256) {
        unsigned pk = pool[i];
        int slot = atomicAdd(&lpos[pk >> 17], 1);
        col[slot] = (int)(pk & 0x1FFFFu);
    }
}

// -------------------------------------------------------------- converters
struct ConvDesc { const float* w; bf16_t* o; int kin; int kpad; };
struct ConvArgs { ConvDesc d[8]; };

__global__ void conv_w_k(ConvArgs args) {
    ConvDesc d = args.d[blockIdx.y];
    int i = blockIdx.x * 256 + threadIdx.x;
    int tot = 128 * d.kpad;
    if (i >= tot) return;
    int n = i / d.kpad, k = i - n * d.kpad;
    float v = (k < d.kin) ? d.w[(size_t)k * 128 + n] : 0.f;
    d.o[i] = (bf16_t)v;
}

__global__ void conv_x_k(const float* __restrict__ x, bf16_t* __restrict__ xb, int n) {
    int i = blockIdx.x * 256 + threadIdx.x;
    if (i >= n * 64) return;
    int node = i >> 6, k = i & 63;
    xb[i] = (k < D_IN) ? (bf16_t)x[node * D_IN + k] : (bf16_t)0.f;
}

// ------------------------------------------------------------- aggregation
// At the structural service-rate ceiling (~7.2 TB/s delivered) — do not
// restructure (rounds 3/4 both regressed trading parallelism for locality).
__global__ void agg_bf64_k(const bf16_t* __restrict__ feat, const int* __restrict__ rp,
                           const int* __restrict__ col, bf16_t* __restrict__ mean, int n) {
    int wid = (blockIdx.x * blockDim.x + threadIdx.x) >> 6;
    int lane = threadIdx.x & 63;
    if (wid >= n) return;
    int start = rp[wid], end = rp[wid + 1];
    int lc = lane & 7;
    int g = lane >> 3;
    f32x2_t accA[4], accB[4];
#pragma unroll
    for (int k = 0; k < 4; k++) { accA[k] = (f32x2_t){0.f, 0.f}; accB[k] = (f32x2_t){0.f, 0.f}; }
    int e = start + g;
    if (e + 8 < end) {
        int i0 = col[e], i1 = col[e + 8];
        for (; e + 24 < end; e += 16) {
            uint4 r0 = *(const uint4*)(feat + (size_t)i0 * 64 + lc * 8);
            uint4 r1 = *(const uint4*)(feat + (size_t)i1 * 64 + lc * 8);
            i0 = col[e + 16];
            i1 = col[e + 24];
            ACCP(r0, accA);
            ACCP(r1, accB);
        }
        uint4 r0 = *(const uint4*)(feat + (size_t)i0 * 64 + lc * 8);
        uint4 r1 = *(const uint4*)(feat + (size_t)i1 * 64 + lc * 8);
        ACCP(r0, accA);
        ACCP(r1, accB);
        e += 16;
    }
    for (; e < end; e += 8) {
        uint4 r0 = *(const uint4*)(feat + (size_t)col[e] * 64 + lc * 8);
        ACCP(r0, accA);
    }
#pragma unroll
    for (int k = 0; k < 4; k++) accA[k] += accB[k];
    float aL[4], aH[4];
#pragma unroll
    for (int k = 0; k < 4; k++) { aL[k] = accA[k].x; aH[k] = accA[k].y; }
#pragma unroll
    for (int off = 8; off < 64; off <<= 1) {
#pragma unroll
        for (int k = 0; k < 4; k++) {
            aL[k] += __shfl_xor(aL[k], off);
            aH[k] += __shfl_xor(aH[k], off);
        }
    }
    int c = end - start;
    float invc = 1.f / (float)(c > 0 ? c : 1);
    if (lane < 8) {
        bf16x8 o;
#pragma unroll
        for (int k = 0; k < 4; k++) {
            o[2 * k] = (bf16_t)(aL[k] * invc);
            o[2 * k + 1] = (bf16_t)(aH[k] * invc);
        }
        *(bf16x8*)(mean + (size_t)wid * 64 + lc * 8) = o;
    }
}

// 4-deep pipelined gather (round-2 best: 56.6 us).
__global__ void agg_bf128_k(const bf16_t* __restrict__ feat, const int* __restrict__ rp,
                            const int* __restrict__ col, bf16_t* __restrict__ mean, int n) {
    int wid = (blockIdx.x * blockDim.x + threadIdx.x) >> 6;
    int lane = threadIdx.x & 63;
    if (wid >= n) return;
    int start = rp[wid], end = rp[wid + 1];
    int lc = lane & 15;
    int g = lane >> 4;
    const uint* fp = (const uint*)feat + lc * 4;   // row stride = 64 uints
    f32x2_t accA[4], accB[4];
#pragma unroll
    for (int k = 0; k < 4; k++) { accA[k] = (f32x2_t){0.f, 0.f}; accB[k] = (f32x2_t){0.f, 0.f}; }
    int e = start + g;
    int ng = (e < end) ? (((end - 1 - e) >> 2) + 1) : 0;
    int it = 0;
    for (; it + 4 <= ng; it += 4, e += 16) {
        int a = col[e], b = col[e + 4], c = col[e + 8], d = col[e + 12];
        uint4 r0 = *(const uint4*)(fp + (size_t)a * 64);
        uint4 r1 = *(const uint4*)(fp + (size_t)b * 64);
        uint4 r2 = *(const uint4*)(fp + (size_t)c * 64);
        uint4 r3 = *(const uint4*)(fp + (size_t)d * 64);
        ACCP(r0, accA);
        ACCP(r1, accB);
        ACCP(r2, accA);
        ACCP(r3, accB);
    }
    int rem = ng - it;
    if (rem > 0) {
        int a = col[e];
        int b = (rem > 1) ? col[e + 4] : a;
        int c = (rem > 2) ? col[e + 8] : b;
        uint4 r0 = *(const uint4*)(fp + (size_t)a * 64);
        uint4 r1 = *(const uint4*)(fp + (size_t)b * 64);
        uint4 r2 = *(const uint4*)(fp + (size_t)c * 64);
        ACCP(r0, accA);
        if (rem > 1) ACCP(r1, accB);
        if (rem > 2) ACCP(r2, accA);
    }
#pragma unroll
    for (int k = 0; k < 4; k++) accA[k] += accB[k];
    float aL[4], aH[4];
#pragma unroll
    for (int k = 0; k < 4; k++) { aL[k] = accA[k].x; aH[k] = accA[k].y; }
#pragma unroll
    for (int off = 16; off < 64; off <<= 1) {
#pragma unroll
        for (int k = 0; k < 4; k++) {
            aL[k] += __shfl_xor(aL[k], off);
            aH[k] += __shfl_xor(aH[k], off);
        }
    }
    int c = end - start;
    float invc = 1.f / (float)(c > 0 ? c : 1);
    if (lane < 16) {
        bf16x8 o;
#pragma unroll
        for (int k = 0; k < 4; k++) {
            o[2 * k] = (bf16_t)(aL[k] * invc);
            o[2 * k + 1] = (bf16_t)(aH[k] * invc);
        }
        *(bf16x8*)(mean + (size_t)wid * 128 + lc * 8) = o;
    }
}

// ------------------------------------------------- fused SAGE linear (MFMA)
// Round-5 structure (both weights LDS, direct stores) + SCATTERED-slot f64
// atomics: blocks add to lnacc[(bid&63)*8] (64B apart) — removes the
// same-line far-atomic serialization that cost ~5-8us/GEMM in rounds 5/7.
template <int KPAD, bool DUAL>
__global__ __launch_bounds__(256) void mfma_gemm_k(
    const bf16_t* __restrict__ A, const bf16_t* __restrict__ B,
    const bf16_t* __restrict__ WlT, const bf16_t* __restrict__ WrT,
    const float* __restrict__ bias,
    bf16_t* __restrict__ out, double* __restrict__ lnacc, int M) {
    constexpr int KC = KPAD / 32;
    constexpr int WELE = 8 * KC * 64 * 8;
    __shared__ bf16_t lwl[WELE];
    __shared__ bf16_t lwr[DUAL ? WELE : 8];
    __shared__ float rsum[4], rsum2[4];

    const int tid = threadIdx.x;
    for (int ch = tid; ch < 8 * KC * 64; ch += 256) {
        int nt = ch / (KC * 64);
        int rem = ch - nt * (KC * 64);
        int c = rem >> 6;
        int ln = rem & 63;
        int mm = ln & 15, qq = ln >> 4;
        size_t srcoff = (size_t)(nt * 16 + mm) * KPAD + c * 32 + qq * 8;
        *(bf16x8*)&lwl[ch * 8] = *(const bf16x8*)(WlT + srcoff);
        if (DUAL) *(bf16x8*)&lwr[ch * 8] = *(const bf16x8*)(WrT + srcoff);
    }
    __syncthreads();

    const int w = tid >> 6;
    const int wid = blockIdx.x * 4 + w;
    const int lane = tid & 63;
    const int row0 = wid * 32;
    const int m = lane & 15;
    const int q = lane >> 4;
    const bool act = row0 < M;

    float lsum = 0.f, lsum2 = 0.f;
    if (act) {
        bf16x8 af[2][KC], bfr[DUAL ? 2 : 1][DUAL ? KC : 1];
#pragma unroll
        for (int s = 0; s < 2; s++) {
            const bf16_t* ar = A + (size_t)(row0 + s * 16 + m) * KPAD + q * 8;
#pragma unroll
            for (int c = 0; c < KC; c++) af[s][c] = *(const bf16x8*)(ar + c * 32);
            if (DUAL) {
                const bf16_t* br = B + (size_t)(row0 + s * 16 + m) * KPAD + q * 8;
#pragma unroll
                for (int c = 0; c < KC; c++) bfr[s][c] = *(const bf16x8*)(br + c * 32);
            }
        }
#pragma unroll
        for (int nt = 0; nt < 8; nt++) {
            f32x4_t acc0 = {0.f, 0.f, 0.f, 0.f};
            f32x4_t acc1 = {0.f, 0.f, 0.f, 0.f};
#pragma unroll
            for (int c = 0; c < KC; c++) {
                bf16x8 wv = *(const bf16x8*)&lwl[((nt * KC + c) * 64 + lane) * 8];
                acc0 = __builtin_amdgcn_mfma_f32_16x16x32_bf16(af[0][c], wv, acc0, 0, 0, 0);
                acc1 = __builtin_amdgcn_mfma_f32_16x16x32_bf16(af[1][c], wv, acc1, 0, 0, 0);
            }
            if (DUAL) {
#pragma unroll
                for (int c = 0; c < KC; c++) {
                    bf16x8 wv = *(const bf16x8*)&lwr[((nt * KC + c) * 64 + lane) * 8];
                    acc0 = __builtin_amdgcn_mfma_f32_16x16x32_bf16(bfr[0][c], wv, acc0, 0, 0, 0);
                    acc1 = __builtin_amdgcn_mfma_f32_16x16x32_bf16(bfr[1][c], wv, acc1, 0, 0, 0);
                }
            }
            float bv = bias ? bias[nt * 16 + m] : 0.f;
#pragma unroll
            for (int s = 0; s < 2; s++) {
                f32x4_t* ap = (s == 0) ? &acc0 : &acc1;
#pragma unroll
                for (int r = 0; r < 4; r++) {
                    int row = row0 + s * 16 + q * 4 + r;
                    if (row < M) {
                        float o = (*ap)[r] + bv;
                        out[(size_t)row * 128 + nt * 16 + m] = (bf16_t)o;
                        lsum += o; lsum2 += o * o;
                    }
                }
            }
        }
    }
    for (int off = 32; off > 0; off >>= 1) {
        lsum += __shfl_down(lsum, off);
        lsum2 += __shfl_down(lsum2, off);
    }
    if (lane == 0) { rsum[w] = lsum; rsum2[w] = lsum2; }
    __syncthreads();
    if (tid == 0) {
        double s = (double)rsum[0] + (double)rsum[1] + (double)rsum[2] + (double)rsum[3];
        double s2 = (double)rsum2[0] + (double)rsum2[1] + (double)rsum2[2] + (double)rsum2[3];
        int slot = (blockIdx.x & (NSLOT - 1)) * 8;
        unsafeAtomicAdd(&lnacc[slot], s);
        unsafeAtomicAdd(&lnacc[slot + 1], s2);
    }
}

// Layer-1 triple — round-6 structure (the only variant measured <57us):
// Wl/Wr in LDS, coalesced LDS-staged stores, Ws1/Ws2 L2-direct passes.
// Plus scattered-slot atomics.
__global__ __launch_bounds__(256) void mfma_gemm3_k(
    const bf16_t* __restrict__ A, const bf16_t* __restrict__ B,
    const bf16_t* __restrict__ WlT, const bf16_t* __restrict__ WrT,
    const bf16_t* __restrict__ Ws1T, const bf16_t* __restrict__ Ws2T,
    const float* __restrict__ bias,
    bf16_t* __restrict__ outP, bf16_t* __restrict__ outC1, bf16_t* __restrict__ outC2,
    double* __restrict__ lnacc, int M) {
    constexpr int KC = 2;
    constexpr int WELE = 8 * KC * 64 * 8;
    __shared__ bf16_t lwl[WELE];
    __shared__ bf16_t lwr[WELE];
    __shared__ __align__(16) bf16_t lst[4][16 * STRIDE_ST];
    __shared__ float rsum[4], rsum2[4];

    const int tid = threadIdx.x;
    for (int ch = tid; ch < 8 * KC * 64; ch += 256) {
        int nt = ch / (KC * 64);
        int rem = ch - nt * (KC * 64);
        int c = rem >> 6;
        int ln = rem & 63;
        int mm = ln & 15, qq = ln >> 4;
        size_t srcoff = (size_t)(nt * 16 + mm) * 64 + c * 32 + qq * 8;
        *(bf16x8*)&lwl[ch * 8] = *(const bf16x8*)(WlT + srcoff);
        *(bf16x8*)&lwr[ch * 8] = *(const bf16x8*)(WrT + srcoff);
    }
    __syncthreads();

    const int w = tid >> 6;
    const int wid = blockIdx.x * 4 + w;
    const int lane = tid & 63;
    const int row0 = wid * 32;
    const int m = lane & 15;
    const int q = lane >> 4;
    const bool act = row0 < M;

    float lsum = 0.f, lsum2 = 0.f;
    if (act) {
        bf16x8 af[2][KC], bfr[2][KC];
#pragma unroll
        for (int s = 0; s < 2; s++) {
            const bf16_t* ar = A + (size_t)(row0 + s * 16 + m) * 64 + q * 8;
            const bf16_t* br = B + (size_t)(row0 + s * 16 + m) * 64 + q * 8;
#pragma unroll
            for (int c = 0; c < KC; c++) {
                af[s][c] = *(const bf16x8*)(ar + c * 32);
                bfr[s][c] = *(const bf16x8*)(br + c * 32);
            }
        }
        bf16_t* st = lst[w];

        // ---- pass P: mean@Wl + x@Wr + bias (stats)
#pragma unroll
        for (int s = 0; s < 2; s++) {
#pragma unroll
            for (int nt = 0; nt < 8; nt++) {
                f32x4_t acc = {0.f, 0.f, 0.f, 0.f};
#pragma unroll
                for (int c = 0; c < KC; c++) {
                    int wi = ((nt * KC + c) * 64 + lane) * 8;
                    bf16x8 wl = *(const bf16x8*)&lwl[wi];
                    bf16x8 wr = *(const bf16x8*)&lwr[wi];
                    acc = __builtin_amdgcn_mfma_f32_16x16x32_bf16(af[s][c], wl, acc, 0, 0, 0);
                    acc = __builtin_amdgcn_mfma_f32_16x16x32_bf16(bfr[s][c], wr, acc, 0, 0, 0);
                }
                float bv = bias[nt * 16 + m];
#pragma unroll
                for (int r = 0; r < 4; r++) {
                    float o = acc[r] + bv;
                    int row = row0 + s * 16 + q * 4 + r;
                    if (row < M) { lsum += o; lsum2 += o * o; }
                    st[(q * 4 + r) * STRIDE_ST + nt * 16 + m] = (bf16_t)o;
                }
            }
            int rowbase = row0 + s * 16;
#pragma unroll
            for (int k = 0; k < 4; k++) {
                int chunk = k * 64 + lane;
                int rr = chunk >> 4;
                int co = (chunk & 15) * 8;
                int row = rowbase + rr;
                bf16x8 v = *(bf16x8*)&st[rr * STRIDE_ST + co];
                if (row < M) *(bf16x8*)(outP + (size_t)row * 128 + co) = v;
            }
        }

        // ---- passes C1, C2: x@Ws (weights L2-direct, no bias, no stats)
#pragma unroll
        for (int p = 0; p < 2; p++) {
            const bf16_t* WT = (p == 0) ? Ws1T : Ws2T;
            bf16_t* outC = (p == 0) ? outC1 : outC2;
#pragma unroll
            for (int s = 0; s < 2; s++) {
#pragma unroll
                for (int nt = 0; nt < 8; nt++) {
                    f32x4_t acc = {0.f, 0.f, 0.f, 0.f};
#pragma unroll
                    for (int c = 0; c < KC; c++) {
                        size_t woff = (size_t)(nt * 16 + m) * 64 + c * 32 + q * 8;
                        bf16x8 wv = *(const bf16x8*)(WT + woff);
                        acc = __builtin_amdgcn_mfma_f32_16x16x32_bf16(bfr[s][c], wv, acc, 0, 0, 0);
                    }
#pragma unroll
                    for (int r = 0; r < 4; r++)
                        st[(q * 4 + r) * STRIDE_ST + nt * 16 + m] = (bf16_t)acc[r];
                }
                int rowbase = row0 + s * 16;
#pragma unroll
                for (int k = 0; k < 4; k++) {
                    int chunk = k * 64 + lane;
                    int rr = chunk >> 4;
                    int co = (chunk & 15) * 8;
                    int row = rowbase + rr;
                    bf16x8 v = *(bf16x8*)&st[rr * STRIDE_ST + co];
                    if (row < M) *(bf16x8*)(outC + (size_t)row * 128 + co) = v;
                }
            }
        }
    }
    for (int off = 32; off > 0; off >>= 1) {
        lsum += __shfl_down(lsum, off);
        lsum2 += __shfl_down(lsum2, off);
    }
    if (lane == 0) { rsum[w] = lsum; rsum2[w] = lsum2; }
    __syncthreads();
    if (tid == 0) {
        double s = (double)rsum[0] + (double)rsum[1] + (double)rsum[2] + (double)rsum[3];
        double s2 = (double)rsum2[0] + (double)rsum2[1] + (double)rsum2[2] + (double)rsum2[3];
        int slot = (blockIdx.x & (NSLOT - 1)) * 8;
        unsafeAtomicAdd(&lnacc[slot], s);
        unsafeAtomicAdd(&lnacc[slot + 1], s2);
    }
}

// --------------------------------------------- LN (graph mode) + PReLU (+skip)
// Slot-reduce preamble (wave 0 folds the 64 scattered stat slots), then
// barrier, then bounds-checked body.
template <int MODE>
__global__ void ln_prelu_k(const bf16_t* __restrict__ pre, const bf16_t* __restrict__ h1in,
                           const bf16_t* __restrict__ s,
                           const float* __restrict__ lnw, const float* __restrict__ lnb,
                           const float* __restrict__ a_ptr, const double* __restrict__ acc,
                           void* __restrict__ out0v, void* __restrict__ out1v, int total) {
    __shared__ double ssum, ssum2;
    int t = threadIdx.x;
    if (t < 64) {
        double a = acc[t * 8];
        double b = acc[t * 8 + 1];
        for (int off = 32; off > 0; off >>= 1) {
            a += __shfl_down(a, off);
            b += __shfl_down(b, off);
        }
        if (t == 0) { ssum = a; ssum2 = b; }
    }
    __syncthreads();
    int i = blockIdx.x * blockDim.x + t;
    if (i * 8 >= total) return;
    double cinv = 1.0 / (double)total;
    double mm = ssum * cinv;
    double var = ssum2 * cinv - mm * mm;
    float stdv = (float)sqrt(var > 0.0 ? var : 0.0);
    float scale = 1.0f / (stdv + LN_EPS);
    float mf = (float)mm;
    float a = a_ptr[0];
    int c8 = i & 15;
    float4 w0 = ((const float4*)lnw)[c8 * 2];
    float4 w1 = ((const float4*)lnw)[c8 * 2 + 1];
    float4 b0 = ((const float4*)lnb)[c8 * 2];
    float4 b1 = ((const float4*)lnb)[c8 * 2 + 1];
    float wv[8] = {w0.x, w0.y, w0.z, w0.w, w1.x, w1.y, w1.z, w1.w};
    float bv[8] = {b0.x, b0.y, b0.z, b0.w, b1.x, b1.y, b1.z, b1.w};
    bf16x8 p8 = ((const bf16x8*)pre)[i];
    float h[8];
#pragma unroll
    for (int k = 0; k < 8; k++) {
        float v = ((float)p8[k] - mf) * scale * wv[k] + bv[k];
        h[k] = v >= 0.f ? v : a * v;
    }
    if (MODE == 1) {
        bf16x8 hb, tb;
        bf16x8 sv = ((const bf16x8*)s)[i];
#pragma unroll
        for (int k = 0; k < 8; k++) {
            hb[k] = (bf16_t)h[k];
            tb[k] = (bf16_t)(h[k] + (float)sv[k]);
        }
        ((bf16x8*)out0v)[i] = hb;
        ((bf16x8*)out1v)[i] = tb;
    } else if (MODE == 2) {
        bf16x8 hv = ((const bf16x8*)h1in)[i];
        bf16x8 sv = ((const bf16x8*)s)[i];
        bf16x8 tb;
#pragma unroll
        for (int k = 0; k < 8; k++)
            tb[k] = (bf16_t)((float)hv[k] + h[k] + (float)sv[k]);
        ((bf16x8*)out0v)[i] = tb;
    } else {
        float4 o0 = {h[0], h[1], h[2], h[3]};
        float4 o1 = {h[4], h[5], h[6], h[7]};
        ((float4*)out0v)[i * 2] = o0;
        ((float4*)out0v)[i * 2 + 1] = o1;
    }
}

// ------------------------------------------------------------------ launch
extern "C" void kernel_launch(void* const* d_in, const int* in_sizes, int n_in,
                              void* d_out, int out_size, void* d_ws, size_t ws_size,
                              hipStream_t stream) {
    const float* x    = (const float*)d_in[0];
    const int*   esrc = (const int*)d_in[1];
    const int*   edst = (const int*)d_in[2];
    const float* Wl1  = (const float*)d_in[3];
    const float* Wr1  = (const float*)d_in[4];
    const float* b1   = (const float*)d_in[5];
    const float* Wl2  = (const float*)d_in[6];
    const float* Wr2  = (const float*)d_in[7];
    const float* b2   = (const float*)d_in[8];
    const float* Wl3  = (const float*)d_in[9];
    const float* Wr3  = (const float*)d_in[10];
    const float* b3   = (const float*)d_in[11];
    const float* Ws1  = (const float*)d_in[12];
    const float* Ws2  = (const float*)d_in[13];
    const float* lnw1 = (const float*)d_in[14];
    const float* lnb1 = (const float*)d_in[15];
    const float* lnw2 = (const float*)d_in[16];
    const float* lnb2 = (const float*)d_in[17];
    const float* lnw3 = (const float*)d_in[18];
    const float* lnb3 = (const float*)d_in[19];
    const float* a1   = (const float*)d_in[20];
    const float* a2   = (const float*)d_in[21];
    const float* a3   = (const float*)d_in[22];

    const int N = in_sizes[0] / D_IN;
    const int E = in_sizes[1];
    const int NB = (N + 255) >> BSH;

    char* ws = (char*)d_ws;
    size_t off = 0;
    auto alloc = [&](size_t bytes) -> void* {
        void* p = ws + off;
        off += (bytes + 255) & ~(size_t)255;
        return p;
    };
    bf16_t* xb   = (bf16_t*)alloc((size_t)N * 64 * 2);
    bf16_t* mean = (bf16_t*)alloc((size_t)N * 128 * 2);
    bf16_t* PRE  = (bf16_t*)alloc((size_t)N * 128 * 2);
    bf16_t* C1   = (bf16_t*)alloc((size_t)N * 128 * 2);
    bf16_t* C2   = (bf16_t*)alloc((size_t)N * 128 * 2);
    bf16_t* h1b  = (bf16_t*)alloc((size_t)N * 128 * 2);
    bf16_t* TB   = (bf16_t*)alloc((size_t)N * 128 * 2);
    bf16_t* WT   = (bf16_t*)alloc((size_t)(4 * 128 * 64 + 4 * 128 * 128) * 2);
    int* rp   = (int*)alloc((size_t)(N + 1) * 4);
    int* col  = (int*)alloc((size_t)E * 4);
    int* bcnt = (int*)alloc((size_t)MAXB * 16 * 4);
    int* boff = (int*)alloc((size_t)(MAXB + 1) * 4);
    int* bpos = (int*)alloc((size_t)MAXB * 16 * 4);
    unsigned* pool = (unsigned*)alloc((size_t)E * 4);
    double* lnacc = (double*)alloc((size_t)3 * NSLOT * 8 * 8);   // 3 layers x 64 slots x 64B

    bf16_t* Wl1T = WT;
    bf16_t* Wr1T = Wl1T + 128 * 64;
    bf16_t* Ws1T = Wr1T + 128 * 64;
    bf16_t* Ws2T = Ws1T + 128 * 64;
    bf16_t* Wl2T = Ws2T + 128 * 64;
    bf16_t* Wr2T = Wl2T + 128 * 128;
    bf16_t* Wl3T = Wr2T + 128 * 128;
    bf16_t* Wr3T = Wl3T + 128 * 128;

    hipMemsetAsync(bcnt, 0, (size_t)MAXB * 16 * 4, stream);

    // --- bucketed CSR build (bucket_hist also re-zeros the lnacc slots)
    bucket_hist_k<<<256, 256, 0, stream>>>(edst, bcnt, lnacc, E, NB);
    bscan_k<<<1, MAXB, 0, stream>>>(bcnt, boff, bpos, NB, E);
    scatter_k<<<256, 256, 0, stream>>>(esrc, edst, bpos, pool, E, NB);
    nhist_cfill_k<<<NB, 256, 0, stream>>>(pool, boff, rp, col, N);

    // --- weight/feature conversion
    ConvArgs ca;
    ca.d[0] = {Wl1, Wl1T, 50, 64};
    ca.d[1] = {Wr1, Wr1T, 50, 64};
    ca.d[2] = {Ws1, Ws1T, 50, 64};
    ca.d[3] = {Ws2, Ws2T, 50, 64};
    ca.d[4] = {Wl2, Wl2T, 128, 128};
    ca.d[5] = {Wr2, Wr2T, 128, 128};
    ca.d[6] = {Wl3, Wl3T, 128, 128};
    ca.d[7] = {Wr3, Wr3T, 128, 128};
    conv_w_k<<<dim3(64, 8), 256, 0, stream>>>(ca);
    conv_x_k<<<(N * 64 + 255) / 256, 256, 0, stream>>>(x, xb, N);

    const int aggBlocks = ((N * 64) + 255) / 256;
    const int tiles = (N + 31) / 32;
    const int gemmBlocks = (tiles + 3) / 4;
    const int lnBlocks = (N * 128 / 8 + 255) / 256;
    const int total = N * 128;
    double* acc1 = lnacc;
    double* acc2 = lnacc + NSLOT * 8;
    double* acc3 = lnacc + 2 * NSLOT * 8;

    // ---- layer 1
    agg_bf64_k<<<aggBlocks, 256, 0, stream>>>(xb, rp, col, mean, N);
    mfma_gemm3_k<<<gemmBlocks, 256, 0, stream>>>(
        mean, xb, Wl1T, Wr1T, Ws1T, Ws2T, b1, PRE, C1, C2, acc1, N);
    ln_prelu_k<1><<<lnBlocks, 256, 0, stream>>>(
        PRE, nullptr, C1, lnw1, lnb1, a1, acc1, h1b, TB, total);

    // ---- layer 2
    agg_bf128_k<<<aggBlocks, 256, 0, stream>>>(TB, rp, col, mean, N);
    mfma_gemm_k<128, true><<<gemmBlocks, 256, 0, stream>>>(
        mean, TB, Wl2T, Wr2T, b2, PRE, acc2, N);
    ln_prelu_k<2><<<lnBlocks, 256, 0, stream>>>(
        PRE, h1b, C2, lnw2, lnb2, a2, acc2, TB, nullptr, total);

    // ---- layer 3
    agg_bf128_k<<<aggBlocks, 256, 0, stream>>>(TB, rp, col, mean, N);
    mfma_gemm_k<128, true><<<gemmBlocks, 256, 0, stream>>>(
        mean, TB, Wl3T, Wr3T, b3, PRE, acc3, N);
    ln_prelu_k<3><<<lnBlocks, 256, 0, stream>>>(
        PRE, nullptr, nullptr, lnw3, lnb3, a3, acc3, d_out, nullptr, total);
}